// Round 3
// baseline (8301.929 us; speedup 1.0000x reference)
//
#include <hip/hip_runtime.h>
#include <math.h>

// ---------------- CSR build ----------------

__global__ void k_zero_i32(int* __restrict__ p, int n) {
    int i = blockIdx.x * blockDim.x + threadIdx.x;
    if (i < n) p[i] = 0;
}

__global__ void k_count_deg(const int* __restrict__ erow, int* __restrict__ deg, int e) {
    for (int i = blockIdx.x * blockDim.x + threadIdx.x; i < e; i += gridDim.x * blockDim.x)
        atomicAdd(&deg[erow[i]], 1);
}

// single-block inclusive scan over degrees -> csr_ptr (exclusive in ptr[i], inclusive in ptr[i+1])
__global__ __launch_bounds__(1024) void k_scan(const int* __restrict__ deg, int* __restrict__ ptr,
                                               int* __restrict__ cursor, int n) {
    __shared__ int buf[1024];
    __shared__ int carry_s;
    int t = threadIdx.x;
    if (t == 0) { carry_s = 0; ptr[0] = 0; }
    __syncthreads();
    for (int base = 0; base < n; base += 1024) {
        int i = base + t;
        int v = (i < n) ? deg[i] : 0;
        buf[t] = v;
        __syncthreads();
        #pragma unroll
        for (int off = 1; off < 1024; off <<= 1) {
            int xv = (t >= off) ? buf[t - off] : 0;
            __syncthreads();
            buf[t] += xv;
            __syncthreads();
        }
        int carry = carry_s;
        int incl = buf[t] + carry;
        if (i < n) { ptr[i + 1] = incl; cursor[i] = incl - v; }
        int bsum = buf[1023];
        __syncthreads();
        if (t == 0) carry_s = carry + bsum;
        __syncthreads();
    }
}

__global__ void k_scatter(const int* __restrict__ erow, const int* __restrict__ ecol,
                          int* __restrict__ cursor, int* __restrict__ csr_col, int e) {
    for (int i = blockIdx.x * blockDim.x + threadIdx.x; i < e; i += gridDim.x * blockDim.x) {
        int pos = atomicAdd(&cursor[erow[i]], 1);
        csr_col[pos] = ecol[i];
    }
}

// ---------------- SpMM1: ax[i][:] = (1/deg_i) * sum_{c in N(i)} x[c][:]   (300-wide, pad to 304) ----------------

__global__ __launch_bounds__(128) void k_spmm1(const int* __restrict__ ptr, const int* __restrict__ col,
                                               const float* __restrict__ x, float* __restrict__ ax) {
    int r = blockIdx.x;
    int t = threadIdx.x;
    int s = ptr[r], epos = ptr[r + 1];
    float a0 = 0.f, a1 = 0.f, a2 = 0.f;
    for (int p = s; p < epos; ++p) {
        const float* xr = x + (size_t)col[p] * 300;
        a0 += xr[t];
        a1 += xr[t + 128];
        if (t < 44) a2 += xr[t + 256];
    }
    float w = 1.0f / fmaxf((float)(epos - s), 1.0f);
    float* o = ax + (size_t)r * 304;
    o[t] = a0 * w;
    o[t + 128] = a1 * w;
    if (t < 44) o[t + 256] = a2 * w;
    if (t >= 44 && t < 48) o[t + 256] = 0.0f;   // zero the K-pad 300..303
}

// ---------------- fp32 tiled GEMM: C[M,N] = A[M,lda(K)] @ B[K,N]  (+bias,+leaky for EPI=1) ----------------

template <int EPI>
__global__ __launch_bounds__(256) void k_gemm(const float* __restrict__ A, int lda,
                                              const float* __restrict__ B,
                                              const float* __restrict__ bias,
                                              float* __restrict__ C,
                                              int M, int N, int K, int Kb) {
    const int BM = 128, BN = 128, BK = 16;
    __shared__ float As[BK][BM];
    __shared__ float Bs[BK][BN];
    int bm = blockIdx.x * BM, bn = blockIdx.y * BN;
    int tid = threadIdx.x;
    int tm = (tid >> 4) << 3;
    int tn = (tid & 15) << 3;
    float acc[8][8] = {};
    for (int k0 = 0; k0 < K; k0 += BK) {
        #pragma unroll
        for (int i = 0; i < 2; ++i) {
            int idx = tid + i * 256;         // 512 float4 in A tile
            int m = idx >> 2;
            int kq = (idx & 3) << 2;
            int row = bm + m; if (row >= M) row = M - 1;
            const float4 v = *reinterpret_cast<const float4*>(A + (size_t)row * lda + k0 + kq);
            As[kq + 0][m] = v.x; As[kq + 1][m] = v.y; As[kq + 2][m] = v.z; As[kq + 3][m] = v.w;
        }
        #pragma unroll
        for (int i = 0; i < 2; ++i) {
            int idx = tid + i * 256;
            int k = idx >> 5;
            int jq = (idx & 31) << 2;
            int krow = k0 + k; if (krow >= Kb) krow = Kb - 1;   // K-pad rows: A is 0 there
            *reinterpret_cast<float4*>(&Bs[k][jq]) =
                *reinterpret_cast<const float4*>(B + (size_t)krow * N + bn + jq);
        }
        __syncthreads();
        #pragma unroll
        for (int kk = 0; kk < BK; ++kk) {
            float a[8], b[8];
            *(float4*)&a[0] = *(const float4*)&As[kk][tm];
            *(float4*)&a[4] = *(const float4*)&As[kk][tm + 4];
            *(float4*)&b[0] = *(const float4*)&Bs[kk][tn];
            *(float4*)&b[4] = *(const float4*)&Bs[kk][tn + 4];
            #pragma unroll
            for (int i = 0; i < 8; ++i)
                #pragma unroll
                for (int j = 0; j < 8; ++j)
                    acc[i][j] = fmaf(a[i], b[j], acc[i][j]);
        }
        __syncthreads();
    }
    #pragma unroll
    for (int i = 0; i < 8; ++i) {
        int row = bm + tm + i;
        if (row >= M) break;
        float vv[8];
        #pragma unroll
        for (int j = 0; j < 8; ++j) {
            float v = acc[i][j];
            if (EPI == 1) {
                v += bias[bn + tn + j];
                v = (v >= 0.f) ? v : 0.2f * v;
            }
            vv[j] = v;
        }
        float* cp = C + (size_t)row * N + bn + tn;
        *(float4*)&cp[0] = *(float4*)&vv[0];
        *(float4*)&cp[4] = *(float4*)&vv[4];
    }
}

// ---------------- SpMM2 + bias + row L2 normalize (2048-wide) ----------------

__global__ __launch_bounds__(256) void k_spmm2_norm(const int* __restrict__ ptr, const int* __restrict__ col,
                                                    const float* __restrict__ H2, const float* __restrict__ b2,
                                                    float* __restrict__ out) {
    const int C = 2048;
    int r = blockIdx.x, t = threadIdx.x;
    int s = ptr[r], e = ptr[r + 1];
    float acc[8] = {0.f, 0.f, 0.f, 0.f, 0.f, 0.f, 0.f, 0.f};
    for (int p = s; p < e; ++p) {
        const float* hr = H2 + (size_t)col[p] * C;
        #pragma unroll
        for (int j = 0; j < 8; ++j) acc[j] += hr[t + j * 256];
    }
    float w = 1.0f / fmaxf((float)(e - s), 1.0f);
    float ss = 0.f;
    #pragma unroll
    for (int j = 0; j < 8; ++j) {
        float v = acc[j] * w + b2[t + j * 256];
        acc[j] = v;
        ss += v * v;
    }
    __shared__ float red[4];
    __shared__ float scale_s;
    #pragma unroll
    for (int off = 32; off > 0; off >>= 1) ss += __shfl_down(ss, off, 64);
    int lane = t & 63, wid = t >> 6;
    if (lane == 0) red[wid] = ss;
    __syncthreads();
    if (t == 0) {
        float tot = red[0] + red[1] + red[2] + red[3];
        scale_s = 1.0f / fmaxf(sqrtf(tot), 1e-12f);
    }
    __syncthreads();
    float sc = scale_s;
    float* o = out + (size_t)r * C;
    #pragma unroll
    for (int j = 0; j < 8; ++j) o[t + j * 256] = acc[j] * sc;
}

// ---------------- launch ----------------

extern "C" void kernel_launch(void* const* d_in, const int* in_sizes, int n_in,
                              void* d_out, int out_size, void* d_ws, size_t ws_size,
                              hipStream_t stream) {
    const float* x  = (const float*)d_in[0];
    const float* W1 = (const float*)d_in[1];
    const float* b1 = (const float*)d_in[2];
    const float* W2 = (const float*)d_in[3];
    const float* b2 = (const float*)d_in[4];
    const int* erow = (const int*)d_in[5];
    const int* ecol = (const int*)d_in[6];

    const int chid = in_sizes[2];              // 2048
    const int cout = in_sizes[4];              // 2048
    const int cin  = in_sizes[1] / chid;       // 300
    const int n    = in_sizes[0] / cin;        // 50000
    const int e    = in_sizes[5];              // 1600000

    char* ws = (char*)d_ws;
    size_t off = 0;
    auto alloc = [&](size_t bytes) -> void* {
        void* p = ws + off;
        off += (bytes + 255) & ~(size_t)255;
        return p;
    };
    int*   deg     = (int*)alloc((size_t)n * 4);
    int*   ptr     = (int*)alloc((size_t)(n + 1) * 4);
    int*   cursor  = (int*)alloc((size_t)n * 4);
    int*   csr_col = (int*)alloc((size_t)e * 4);
    float* ax      = (float*)alloc((size_t)n * 304 * 4);
    float* H2      = (float*)alloc((size_t)n * (size_t)cout * 4);
    float* H1      = (float*)d_out;            // reuse d_out as H1 scratch

    k_zero_i32<<<(n + 255) / 256, 256, 0, stream>>>(deg, n);
    k_count_deg<<<2048, 256, 0, stream>>>(erow, deg, e);
    k_scan<<<1, 1024, 0, stream>>>(deg, ptr, cursor, n);
    k_scatter<<<2048, 256, 0, stream>>>(erow, ecol, cursor, csr_col, e);

    k_spmm1<<<n, 128, 0, stream>>>(ptr, csr_col, x, ax);

    dim3 g1((n + 127) / 128, chid / 128);
    // H1 = LeakyReLU((A@X) @ W1 + b1)
    k_gemm<1><<<g1, 256, 0, stream>>>(ax, 304, W1, b1, H1, n, chid, 304, cin);

    dim3 g2((n + 127) / 128, cout / 128);
    // H2 = H1 @ W2
    k_gemm<0><<<g2, 256, 0, stream>>>(H1, chid, W2, b2, H2, n, cout, chid, chid);

    // out = normalize(A @ H2 + b2)
    k_spmm2_norm<<<n, 256, 0, stream>>>(ptr, csr_col, H2, b2, (float*)d_out);
}

// Round 4
// 2341.707 us; speedup vs baseline: 3.5452x; 3.5452x over previous
//
#include <hip/hip_runtime.h>
#include <math.h>

typedef unsigned short ushort_t;
using bf16x8  = __attribute__((ext_vector_type(8))) short;
using f32x4   = __attribute__((ext_vector_type(4))) float;
using ushort8 = __attribute__((ext_vector_type(8))) unsigned short;

__device__ __forceinline__ unsigned short f2bf(float f) {
    union { float f; unsigned int u; } v; v.f = f;
    unsigned int r = v.u + 0x7FFFu + ((v.u >> 16) & 1u);   // RNE
    return (unsigned short)(r >> 16);
}
__device__ __forceinline__ float bf2f(unsigned short u) {
    union { unsigned int u; float f; } v; v.u = ((unsigned int)u) << 16;
    return v.f;
}

typedef const __attribute__((address_space(1))) void* gas_ptr;
typedef __attribute__((address_space(3))) void* las_ptr;
__device__ __forceinline__ void gload16(const void* g, void* l) {
    __builtin_amdgcn_global_load_lds((gas_ptr)g, (las_ptr)l, 16, 0, 0);
}

// ---------------- CSR build ----------------

__global__ void k_zero_i32(int* __restrict__ p, int n) {
    int i = blockIdx.x * blockDim.x + threadIdx.x;
    if (i < n) p[i] = 0;
}

__global__ void k_count_deg(const int* __restrict__ erow, int* __restrict__ deg, int e) {
    for (int i = blockIdx.x * blockDim.x + threadIdx.x; i < e; i += gridDim.x * blockDim.x)
        atomicAdd(&deg[erow[i]], 1);
}

__global__ __launch_bounds__(1024) void k_scan(const int* __restrict__ deg, int* __restrict__ ptr,
                                               int* __restrict__ cursor, int n) {
    __shared__ int buf[1024];
    __shared__ int carry_s;
    int t = threadIdx.x;
    if (t == 0) { carry_s = 0; ptr[0] = 0; }
    __syncthreads();
    for (int base = 0; base < n; base += 1024) {
        int i = base + t;
        int v = (i < n) ? deg[i] : 0;
        buf[t] = v;
        __syncthreads();
        #pragma unroll
        for (int off = 1; off < 1024; off <<= 1) {
            int xv = (t >= off) ? buf[t - off] : 0;
            __syncthreads();
            buf[t] += xv;
            __syncthreads();
        }
        int carry = carry_s;
        int incl = buf[t] + carry;
        if (i < n) { ptr[i + 1] = incl; cursor[i] = incl - v; }
        int bsum = buf[1023];
        __syncthreads();
        if (t == 0) carry_s = carry + bsum;
        __syncthreads();
    }
}

__global__ void k_scatter(const int* __restrict__ erow, const int* __restrict__ ecol,
                          int* __restrict__ cursor, int* __restrict__ csr_col, int e) {
    for (int i = blockIdx.x * blockDim.x + threadIdx.x; i < e; i += gridDim.x * blockDim.x) {
        int pos = atomicAdd(&cursor[erow[i]], 1);
        csr_col[pos] = ecol[i];
    }
}

// ---------------- transpose + fp32->bf16: WT[n][kp] = bf16(W[kp][n]), kp>=K -> 0 ----------------

__global__ __launch_bounds__(256) void k_cvt_wT(const float* __restrict__ W, unsigned short* __restrict__ WT,
                                                int K, int N, int Kpad) {
    __shared__ float tile[32][33];
    int kp0 = blockIdx.x * 32, n0 = blockIdx.y * 32;
    int tx = threadIdx.x & 31, ty = threadIdx.x >> 5;   // 32 x 8
    #pragma unroll
    for (int ii = 0; ii < 4; ++ii) {
        int k = kp0 + ty + ii * 8;
        tile[ty + ii * 8][tx] = (k < K) ? W[(size_t)k * N + n0 + tx] : 0.0f;
    }
    __syncthreads();
    #pragma unroll
    for (int ii = 0; ii < 4; ++ii) {
        int n = n0 + ty + ii * 8;
        WT[(size_t)n * Kpad + kp0 + tx] = f2bf(tile[tx][ty + ii * 8]);
    }
}

// ---------------- SpMM1: ax[i][:] = bf16( (1/deg_i) * sum x[col][:] ), 300-wide padded to 320 ----------------

__global__ __launch_bounds__(128) void k_spmm1(const int* __restrict__ ptr, const int* __restrict__ col,
                                               const float* __restrict__ x, unsigned short* __restrict__ ax) {
    int r = blockIdx.x;
    int t = threadIdx.x;
    int s = ptr[r], epos = ptr[r + 1];
    float a0 = 0.f, a1 = 0.f, a2 = 0.f;
    for (int p = s; p < epos; ++p) {
        const float* xr = x + (size_t)col[p] * 300;
        a0 += xr[t];
        a1 += xr[t + 128];
        if (t < 44) a2 += xr[t + 256];
    }
    float w = 1.0f / fmaxf((float)(epos - s), 1.0f);
    unsigned short* o = ax + (size_t)r * 320;
    o[t] = f2bf(a0 * w);
    o[t + 128] = f2bf(a1 * w);
    if (t < 44) o[t + 256] = f2bf(a2 * w);
    if (t >= 44 && t < 64) o[t + 256] = 0;     // pad cols 300..319
}

// ---------------- bf16 MFMA GEMM: C[M][N] = A[M][lda] @ BT[N][ldb]^T  (m97-style 128x128x32) ----------------
// EPI=1: C = bf16(leaky(acc + bias));  EPI=0: C = bf16(acc)

template <int EPI>
__global__ __launch_bounds__(256) void k_mfma_gemm(const unsigned short* __restrict__ A, int lda,
                                                   const unsigned short* __restrict__ BT, int ldb,
                                                   const float* __restrict__ bias,
                                                   unsigned short* __restrict__ C,
                                                   int M, int N, int K) {
    __shared__ __align__(16) unsigned short As[128 * 32];
    __shared__ __align__(16) unsigned short Bs[128 * 32];
    int tid = threadIdx.x;
    int lane = tid & 63;
    int wid = tid >> 6;
    int wm = wid >> 1, wn = wid & 1;                 // 2x2 waves, 64x64 each
    int bm = blockIdx.x * 128, bn = blockIdx.y * 128;

    f32x4 zero4 = {0.f, 0.f, 0.f, 0.f};
    f32x4 acc[4][4];
    #pragma unroll
    for (int i = 0; i < 4; ++i)
        #pragma unroll
        for (int j = 0; j < 4; ++j) acc[i][j] = zero4;

    int srow = tid >> 2;                // 0..63
    int scol = (tid & 3) * 8;           // k-elem offset (16B)
    int ar0 = bm + srow;      if (ar0 >= M) ar0 = M - 1;
    int ar1 = bm + srow + 64; if (ar1 >= M) ar1 = M - 1;
    const unsigned short* gA0 = A + (size_t)ar0 * lda + scol;
    const unsigned short* gA1 = A + (size_t)ar1 * lda + scol;
    const unsigned short* gB0 = BT + (size_t)(bn + srow) * ldb + scol;
    const unsigned short* gB1 = BT + (size_t)(bn + srow + 64) * ldb + scol;

    int kq = (lane >> 4) * 8;           // k-slice within tile: 0/8/16/24
    int rsel = lane & 15;

    for (int k0 = 0; k0 < K; k0 += 32) {
        gload16(gA0 + k0, &As[(size_t)tid * 8]);
        gload16(gA1 + k0, &As[(size_t)(tid + 256) * 8]);
        gload16(gB0 + k0, &Bs[(size_t)tid * 8]);
        gload16(gB1 + k0, &Bs[(size_t)(tid + 256) * 8]);
        __syncthreads();

        bf16x8 af[4], bfr[4];
        #pragma unroll
        for (int i = 0; i < 4; ++i) {
            af[i]  = *(const bf16x8*)&As[(wm * 64 + i * 16 + rsel) * 32 + kq];
            bfr[i] = *(const bf16x8*)&Bs[(wn * 64 + i * 16 + rsel) * 32 + kq];
        }
        #pragma unroll
        for (int i = 0; i < 4; ++i)
            #pragma unroll
            for (int j = 0; j < 4; ++j)
                acc[i][j] = __builtin_amdgcn_mfma_f32_16x16x32_bf16(af[i], bfr[j], acc[i][j], 0, 0, 0);
        __syncthreads();
    }

    // C/D layout (m89-verified): col = lane&15, row = (lane>>4)*4 + reg
    #pragma unroll
    for (int i = 0; i < 4; ++i) {
        int row_base = bm + wm * 64 + i * 16 + (lane >> 4) * 4;
        #pragma unroll
        for (int j = 0; j < 4; ++j) {
            int colg = bn + wn * 64 + j * 16 + (lane & 15);
            float bv = (EPI == 1) ? bias[colg] : 0.0f;
            #pragma unroll
            for (int r = 0; r < 4; ++r) {
                int row = row_base + r;
                if (row < M) {
                    float v = acc[i][j][r];
                    if (EPI == 1) { v += bv; v = (v >= 0.f) ? v : 0.2f * v; }
                    C[(size_t)row * N + colg] = f2bf(v);
                }
            }
        }
    }
}

// ---------------- SpMM2 (bf16 H2) + bias + row L2 normalize ----------------

__global__ __launch_bounds__(256) void k_spmm2_norm(const int* __restrict__ ptr, const int* __restrict__ col,
                                                    const unsigned short* __restrict__ H2,
                                                    const float* __restrict__ b2,
                                                    float* __restrict__ out) {
    const int C = 2048;
    int r = blockIdx.x, t = threadIdx.x;
    int s = ptr[r], e = ptr[r + 1];
    float acc[8] = {0.f, 0.f, 0.f, 0.f, 0.f, 0.f, 0.f, 0.f};
    for (int p = s; p < e; ++p) {
        const unsigned short* hr = H2 + (size_t)col[p] * C + t * 8;
        ushort8 v = *(const ushort8*)hr;
        #pragma unroll
        for (int j = 0; j < 8; ++j) acc[j] += bf2f(v[j]);
    }
    float w = 1.0f / fmaxf((float)(e - s), 1.0f);
    float ss = 0.f;
    #pragma unroll
    for (int j = 0; j < 8; ++j) {
        float v = acc[j] * w + b2[t * 8 + j];
        acc[j] = v;
        ss += v * v;
    }
    __shared__ float red[4];
    __shared__ float scale_s;
    #pragma unroll
    for (int off = 32; off > 0; off >>= 1) ss += __shfl_down(ss, off, 64);
    int lane = t & 63, wid = t >> 6;
    if (lane == 0) red[wid] = ss;
    __syncthreads();
    if (t == 0) {
        float tot = red[0] + red[1] + red[2] + red[3];
        scale_s = 1.0f / fmaxf(sqrtf(tot), 1e-12f);
    }
    __syncthreads();
    float sc = scale_s;
    float* o = out + (size_t)r * C + t * 8;
    float vv[8];
    #pragma unroll
    for (int j = 0; j < 8; ++j) vv[j] = acc[j] * sc;
    *(float4*)&o[0] = *(float4*)&vv[0];
    *(float4*)&o[4] = *(float4*)&vv[4];
}

// ---------------- launch ----------------

extern "C" void kernel_launch(void* const* d_in, const int* in_sizes, int n_in,
                              void* d_out, int out_size, void* d_ws, size_t ws_size,
                              hipStream_t stream) {
    const float* x  = (const float*)d_in[0];
    const float* W1 = (const float*)d_in[1];
    const float* b1 = (const float*)d_in[2];
    const float* W2 = (const float*)d_in[3];
    const float* b2 = (const float*)d_in[4];
    const int* erow = (const int*)d_in[5];
    const int* ecol = (const int*)d_in[6];

    const int chid = in_sizes[2];              // 2048
    const int cout = in_sizes[4];              // 2048
    const int cin  = in_sizes[1] / chid;       // 300
    const int n    = in_sizes[0] / cin;        // 50000
    const int e    = in_sizes[5];              // 1600000
    const int cinp = (cin + 31) & ~31;         // 320 (K-pad for MFMA)

    char* ws = (char*)d_ws;
    size_t off = 0;
    auto alloc = [&](size_t bytes) -> void* {
        void* p = ws + off;
        off += (bytes + 255) & ~(size_t)255;
        return p;
    };
    int*            deg     = (int*)alloc((size_t)n * 4);
    int*            ptr     = (int*)alloc((size_t)(n + 1) * 4);
    int*            cursor  = (int*)alloc((size_t)n * 4);
    int*            csr_col = (int*)alloc((size_t)e * 4);
    unsigned short* ax      = (unsigned short*)alloc((size_t)n * cinp * 2);
    unsigned short* W1T     = (unsigned short*)alloc((size_t)chid * cinp * 2);
    unsigned short* W2T     = (unsigned short*)alloc((size_t)cout * chid * 2);
    unsigned short* H2      = (unsigned short*)alloc((size_t)n * cout * 2);
    unsigned short* H1      = (unsigned short*)d_out;   // bf16 H1 stashed in d_out; fully overwritten at the end

    k_zero_i32<<<(n + 255) / 256, 256, 0, stream>>>(deg, n);
    k_count_deg<<<2048, 256, 0, stream>>>(erow, deg, e);
    k_scan<<<1, 1024, 0, stream>>>(deg, ptr, cursor, n);
    k_scatter<<<2048, 256, 0, stream>>>(erow, ecol, cursor, csr_col, e);

    dim3 gw1(cinp / 32, chid / 32);
    k_cvt_wT<<<gw1, 256, 0, stream>>>(W1, W1T, cin, chid, cinp);
    dim3 gw2(chid / 32, cout / 32);
    k_cvt_wT<<<gw2, 256, 0, stream>>>(W2, W2T, chid, cout, chid);

    k_spmm1<<<n, 128, 0, stream>>>(ptr, csr_col, x, ax);

    dim3 g1((n + 127) / 128, chid / 128);
    // H1 = bf16(LeakyReLU((A@X)bf16 @ W1 + b1))
    k_mfma_gemm<1><<<g1, 256, 0, stream>>>(ax, cinp, W1T, cinp, b1, H1, n, chid, cinp);

    dim3 g2((n + 127) / 128, cout / 128);
    // H2 = bf16(H1 @ W2)
    k_mfma_gemm<0><<<g2, 256, 0, stream>>>(H1, chid, W2T, chid, (const float*)nullptr, H2, n, cout, chid);

    // out = normalize(A @ H2 + b2)
    k_spmm2_norm<<<n, 256, 0, stream>>>(ptr, csr_col, H2, b2, (float*)d_out);
}